// Round 4
// baseline (25.928 us; speedup 1.0000x reference)
//
#include <hip/hip_runtime.h>
#include <hip/hip_cooperative_groups.h>
#include <math.h>

namespace cg = cooperative_groups;

// STP forward as affine recurrence on r = imu/mu:
//   d[n] = a + (x[n-1]+x[n])/2
//   r[n] = exp(-d[n]) * (r[n-1] + x[n-1]/2) + x[n]/2
// td[n] = (r[n] > 0) ? 1 - r[n] : 1 ; chunk(500)-boundary carry clamp r>0?r:1.
// Carry influence decays by exp(-500a) <= ~1e-11 across a chunk, so each
// chunk's raw end is computed carry-free from its own 20 segment (A,B)s.
//
// Fused cooperative kernel: block = (chunk c, batch b), 320 thr = 20 seg x 16 u.
//   phase 1: 25-step f64 affine (A,B) via factored exp (one deg-12 Taylor/step),
//            LDS prefix scan -> (P,Q) in REGISTERS, s==19 stores rraw[c].
//   grid.sync()
//   phase 2: r_in = P*clamp(rraw[c-1]) + Q, 25-step f32 replay (__expf),
//            input re-read hits same-XCD L2 (b == blockIdx%8 -> XCD-pinned).
// Fallback (if co-residency/coop launch unavailable): round-3 two-kernel path.

#define TDIM 50000
#define UDIM 16
#define NCH 100
#define SEG 20      // 25-step sub-segments per chunk
#define SLEN 25
#define NSEQ 128    // B*U

struct alignas(16) PQt { double P; double Q; };

__device__ __forceinline__ float clean(float v) { return (v != v) ? 0.0f : v; }

// exp(y) for |y| <= ~0.7, deg-12 Taylor Horner. rel err < ~2e-12.
__device__ __forceinline__ double exp_small(double y) {
    double p = 2.08767569878681e-9;          // 1/12!
    p = fma(p, y, 2.505210838544172e-8);     // 1/11!
    p = fma(p, y, 2.755731922398589e-7);     // 1/10!
    p = fma(p, y, 2.7557319223985893e-6);    // 1/9!
    p = fma(p, y, 2.48015873015873e-5);      // 1/8!
    p = fma(p, y, 1.984126984126984e-4);     // 1/7!
    p = fma(p, y, 1.3888888888888889e-3);    // 1/6!
    p = fma(p, y, 8.333333333333333e-3);     // 1/5!
    p = fma(p, y, 4.1666666666666664e-2);    // 1/4!
    p = fma(p, y, 1.6666666666666666e-1);    // 1/3!
    p = fma(p, y, 0.5);                      // 1/2!
    p = fma(p, y, 1.0);
    p = fma(p, y, 1.0);
    return p;
}

__global__ __launch_bounds__(320, 5) void stp_fused(
    const float* __restrict__ inp, const float* __restrict__ uu,
    const float* __restrict__ tauv, double* __restrict__ rraw,
    float* __restrict__ out)
{
    const int c = blockIdx.x >> 3;           // chunk 0..99
    const int b = blockIdx.x & 7;            // batch 0..7  (== XCD id)
    const int s = threadIdx.x >> 4;          // seg-in-chunk 0..19
    const int u = threadIdx.x & 15;
    const int n0 = c * 500 + s * SLEN;

    // Replicate reference f32 -> f64 promotion exactly:
    const float ui   = (fabsf(uu[u]) / 100.0f) * 100.0f;
    const float taui = fmaxf(fabsf(tauv[u]), 0.02001f) * 100.0f;
    const float af   = 1.0f / taui;          // f32 divide (as in reference)
    const double a   = (double)af;
    const double ea  = exp(-a);              // loop-invariant, libm

    const float* p = inp + ((size_t)b * TDIM + n0) * UDIM + u;

    // ---- phase 1: f64 segment composition (A,B) ----
    double xp = (n0 != 0) ? (double)(ui * clean(p[-UDIM])) : 0.0;
    double ep = exp_small(-0.5 * xp);        // exp(-xp/2), carried step-to-step
    double A = 1.0, B = 0.0;
#pragma unroll 5
    for (int t = 0; t < SLEN; ++t) {
        const double x  = (double)(ui * clean(p[(size_t)t * UDIM]));
        const double ex = exp_small(-0.5 * x);
        const double e  = ea * ep * ex;      // exp(-(a + (xp+x)/2))
        A *= e;
        B = fma(e, fma(xp, 0.5, B), 0.5 * x);
        ep = ex; xp = x;
    }

    __shared__ double sA[SEG][16];
    __shared__ double sB[SEG][16];
    sA[s][u] = A;
    sB[s][u] = B;
    __syncthreads();

    // exclusive prefix over segs 0..s-1: r_in(seg s) = P*r_chunk_in + Q
    double P = 1.0, Q = 0.0;
    for (int j = 0; j < s; ++j) {
        const double Aj = sA[j][u];
        const double Bj = sB[j][u];
        P *= Aj;
        Q = fma(Aj, Q, Bj);
    }
    const int sbu = b * 16 + u;
    if (s == SEG - 1) {
        // raw chunk end from r_in = 0
        rraw[(size_t)c * NSEQ + sbu] = fma(A, Q, B);
    }

    __threadfence();
    cg::this_grid().sync();

    // ---- phase 2: f32 replay ----
    double carry = 0.0, tdp_d = 1.0;         // chunk 0: imu0=0; out[0] pad=1
    if (c > 0) {
        const double re = rraw[(size_t)(c - 1) * NSEQ + sbu];
        carry = (re > 0.0) ? re : 1.0;       // clamped carry
        tdp_d = (re > 0.0) ? 1.0 - re : 1.0; // td from RAW end of prev chunk
    }
    const double r_in = fma(P, carry, Q);
    if (s > 0) tdp_d = (r_in > 0.0) ? 1.0 - r_in : 1.0;

    float* o = out + ((size_t)b * TDIM + n0) * UDIM + u;
    float xpf = (n0 != 0) ? ui * clean(p[-UDIM]) : 0.0f;
    float r   = (float)r_in;
    float tdp = (float)tdp_d;
#pragma unroll 5
    for (int t = 0; t < SLEN; ++t) {
        const float ts = clean(p[(size_t)t * UDIM]);   // L2-hit re-read
        const float x  = ui * ts;
        const float d  = af + (xpf + x) * 0.5f;
        const float e  = __expf(-d);
        r = e * (r + xpf * 0.5f) + x * 0.5f;
        o[(size_t)t * UDIM] = ts * tdp;      // out[n] = tstim[n]*td[n-1]
        tdp = (r > 0.0f) ? 1.0f - r : 1.0f;
        xpf = x;
    }
}

// ---------------- fallback: round-3 two-kernel path ----------------

__global__ __launch_bounds__(320, 4) void stp_kA(
    const float* __restrict__ inp, const float* __restrict__ uu,
    const float* __restrict__ tauv, PQt* __restrict__ PQ,
    double* __restrict__ rraw)
{
    const int c = blockIdx.x >> 3;
    const int b = blockIdx.x & 7;
    const int s = threadIdx.x >> 4;
    const int u = threadIdx.x & 15;
    const int n0 = c * 500 + s * SLEN;

    const float ui   = (fabsf(uu[u]) / 100.0f) * 100.0f;
    const float taui = fmaxf(fabsf(tauv[u]), 0.02001f) * 100.0f;
    const double a   = (double)(1.0f / taui);
    const double ea  = exp(-a);

    const float* p = inp + ((size_t)b * TDIM + n0) * UDIM + u;
    double xp = (n0 != 0) ? (double)(ui * clean(p[-UDIM])) : 0.0;
    double ep = exp_small(-0.5 * xp);
    double A = 1.0, B = 0.0;
#pragma unroll 5
    for (int t = 0; t < SLEN; ++t) {
        const double x  = (double)(ui * clean(p[(size_t)t * UDIM]));
        const double ex = exp_small(-0.5 * x);
        const double e  = ea * ep * ex;
        A *= e;
        B = fma(e, fma(xp, 0.5, B), 0.5 * x);
        ep = ex; xp = x;
    }

    __shared__ double sA[SEG][16];
    __shared__ double sB[SEG][16];
    sA[s][u] = A;
    sB[s][u] = B;
    __syncthreads();

    double P = 1.0, Q = 0.0;
    for (int j = 0; j < s; ++j) {
        const double Aj = sA[j][u];
        const double Bj = sB[j][u];
        P *= Aj;
        Q = fma(Aj, Q, Bj);
    }

    const int sbu = b * 16 + u;
    PQ[((size_t)c * SEG + s) * NSEQ + sbu] = {P, Q};
    if (s == SEG - 1) rraw[(size_t)c * NSEQ + sbu] = fma(A, Q, B);
}

__global__ __launch_bounds__(128, 4) void stp_kB(
    const float* __restrict__ inp, const float* __restrict__ uu,
    const float* __restrict__ tauv, const PQt* __restrict__ PQ,
    const double* __restrict__ rraw, float* __restrict__ out)
{
    const int tid = blockIdx.x * 128 + threadIdx.x;
    const int sbu = tid & (NSEQ - 1);
    const int seg = tid >> 7;
    const int c   = seg / SEG;
    const int s   = seg - c * SEG;
    const int u   = sbu & 15;
    const int b   = sbu >> 4;
    const int n0  = seg * SLEN;

    const float ui   = (fabsf(uu[u]) / 100.0f) * 100.0f;
    const float taui = fmaxf(fabsf(tauv[u]), 0.02001f) * 100.0f;
    const float af   = 1.0f / taui;

    const PQt pq = PQ[(size_t)seg * NSEQ + sbu];
    double carry = 0.0, tdp_d = 1.0;
    if (c > 0) {
        const double re = rraw[(size_t)(c - 1) * NSEQ + sbu];
        carry = (re > 0.0) ? re : 1.0;
        tdp_d = (re > 0.0) ? 1.0 - re : 1.0;
    }
    const double r_in = fma(pq.P, carry, pq.Q);
    if (s > 0) tdp_d = (r_in > 0.0) ? 1.0 - r_in : 1.0;

    const float* p = inp + ((size_t)b * TDIM + n0) * UDIM + u;
    float*       o = out + ((size_t)b * TDIM + n0) * UDIM + u;
    float xp = (n0 != 0) ? ui * clean(p[-UDIM]) : 0.0f;

    float r   = (float)r_in;
    float tdp = (float)tdp_d;
#pragma unroll 5
    for (int t = 0; t < SLEN; ++t) {
        const float ts = clean(p[(size_t)t * UDIM]);
        const float x  = ui * ts;
        const float d  = af + (xp + x) * 0.5f;
        const float e  = __expf(-d);
        r = e * (r + xp * 0.5f) + x * 0.5f;
        o[(size_t)t * UDIM] = ts * tdp;
        tdp = (r > 0.0f) ? 1.0f - r : 1.0f;
        xp = x;
    }
}

extern "C" void kernel_launch(void* const* d_in, const int* in_sizes, int n_in,
                              void* d_out, int out_size, void* d_ws, size_t ws_size,
                              hipStream_t stream) {
    const float* inp  = (const float*)d_in[0];
    const float* uu   = (const float*)d_in[1];
    const float* tauv = (const float*)d_in[2];
    float* out = (float*)d_out;

    PQt*    PQ   = (PQt*)d_ws;                          // 4,096,000 B (fallback)
    double* rraw = (double*)((char*)d_ws + 4096000);    // 102,400 B

    // Cooperative path: all 800 blocks must be co-resident (>=4 blocks/CU).
    int maxB = 0;
    hipError_t qerr = hipOccupancyMaxActiveBlocksPerMultiprocessor(
        &maxB, stp_fused, 320, 0);
    if (qerr == hipSuccess && maxB * 256 >= NCH * 8) {
        void* args[] = { (void*)&inp, (void*)&uu, (void*)&tauv,
                         (void*)&rraw, (void*)&out };
        hipError_t lerr = hipLaunchCooperativeKernel(
            (const void*)stp_fused, dim3(NCH * 8), dim3(320), args, 0, stream);
        if (lerr == hipSuccess) return;
    }

    // Fallback: two-kernel path (round-3 structure, known-good).
    stp_kA<<<dim3(NCH * 8), dim3(320), 0, stream>>>(inp, uu, tauv, PQ, rraw);
    stp_kB<<<dim3(2000), dim3(128), 0, stream>>>(inp, uu, tauv, PQ, rraw, out);
}